// Round 3
// baseline (21823.570 us; speedup 1.0000x reference)
//
#include <hip/hip_runtime.h>
#include <hip/hip_bf16.h>

// SliceLSTM persistent kernel for gfx950. ALL INPUTS/OUTPUTS ARE F32
// (reference dtype). MFMA is bf16-only, so every operand is split into
// hi/lo double-bf16 and products use 3 terms (ah*bh + al*bh + ah*bl).
// 32 blocks x 256 threads; each block owns 16 h-columns end-to-end.
// W1 hi/lo + W2 hi live in LDS (118 KB); W2 lo streams from L2.
// Sequential recurrence via hand-rolled device-scope grid barrier (2/step).

typedef unsigned short u16;
typedef __attribute__((ext_vector_type(8))) short short8;
typedef __attribute__((ext_vector_type(4))) float floatx4;

#define NB 32
#define NT 256
#define TSTEPS 512

// ---- workspace layout (bytes) ----
#define WS_CNT 0
#define WS_ACT_HI 256
#define WS_ACT_LO (WS_ACT_HI + 262144)
#define WS_H_HI (WS_ACT_LO + 262144)
#define WS_H_LO (WS_H_HI + 65536)
#define WS_CBUF (WS_H_LO + 65536)
#define WS_ZERO_BYTES (WS_CBUF + 131072)           // 786688: zeroed every call
#define WS_W1HI (WS_ZERO_BYTES)                    // 32 blk * 64 row * 192 k * 2B
#define WS_W1LO (WS_W1HI + 786432)
#define WS_W2HI (WS_W1LO + 786432)                 // 32 blk * 64 row * 512 k * 2B
#define WS_W2LO (WS_W2HI + 2097152)

__device__ __forceinline__ float b2f(u16 u) {
  unsigned v = ((unsigned)u) << 16;
  float f;
  __builtin_memcpy(&f, &v, 4);
  return f;
}
__device__ __forceinline__ u16 f2b(float f) {
  __hip_bfloat16 h = __float2bfloat16(f);  // RNE
  u16 u;
  __builtin_memcpy(&u, &h, 2);
  return u;
}
__device__ __forceinline__ float sigf(float x) { return 1.0f / (1.0f + __expf(-x)); }
__device__ __forceinline__ float tanhf_fast(float x) { return 2.0f * sigf(2.0f * x) - 1.0f; }
__device__ __forceinline__ short8 ld8(const u16* p) { return *(const short8*)p; }

__device__ __forceinline__ void split8(const float* p, short8& hi, short8& lo) {
  float4 a = *(const float4*)p;
  float4 b = *(const float4*)(p + 4);
  float v[8] = {a.x, a.y, a.z, a.w, b.x, b.y, b.z, b.w};
#pragma unroll
  for (int i = 0; i < 8; ++i) {
    u16 h = f2b(v[i]);
    hi[i] = (short)h;
    lo[i] = (short)f2b(v[i] - b2f(h));
  }
}

__device__ __forceinline__ void grid_barrier(unsigned* cnt, unsigned target) {
  __threadfence();  // release: drain stores to device scope
  __syncthreads();
  if (threadIdx.x == 0) {
    atomicAdd(cnt, 1u);
    while (__hip_atomic_load(cnt, __ATOMIC_RELAXED, __HIP_MEMORY_SCOPE_AGENT) < target)
      __builtin_amdgcn_s_sleep(1);
  }
  __syncthreads();
  __threadfence();  // acquire
}

__global__ void __launch_bounds__(NT) init_ws_kernel(unsigned* w, int n) {
  int i = blockIdx.x * blockDim.x + threadIdx.x;
  const int st = gridDim.x * blockDim.x;
  for (; i < n; i += st) w[i] = 0u;
}

// split Ws/Us (f32) into per-block k-contiguous bf16 hi/lo tiles
__global__ void __launch_bounds__(NT) prep_w1_kernel(const float* __restrict__ Ws,
                                                     const float* __restrict__ Us,
                                                     u16* __restrict__ w1hi,
                                                     u16* __restrict__ w1lo) {
  const int idx = blockIdx.x * NT + threadIdx.x;  // < 4*192*512
  const int c = idx & 511;
  const int rest = idx >> 9;
  const int k = rest % 192;
  const int s = rest / 192;
  const float w = (k < 64) ? Ws[(size_t)(s * 64 + k) * 512 + c]
                           : Us[(size_t)(s * 128 + (k - 64)) * 512 + c];
  const u16 hi = f2b(w);
  const u16 lo = f2b(w - b2f(hi));
  const int g = c >> 7, cs = c & 127;
  const int blk = s * 8 + (cs >> 4), jj = cs & 15;
  const int dst = blk * 12288 + (g * 16 + jj) * 192 + k;
  w1hi[dst] = hi;
  w1lo[dst] = lo;
}

// split Wc (f32, [k=512][j=2048]) into per-block k-contiguous bf16 hi/lo
__global__ void __launch_bounds__(NT) prep_w2_kernel(const float* __restrict__ Wc,
                                                     u16* __restrict__ w2hi,
                                                     u16* __restrict__ w2lo) {
  __shared__ u16 th[256 * 40];
  __shared__ u16 tl[256 * 40];
  const int tid = threadIdx.x;
  const int k0 = (blockIdx.x >> 3) * 32;
  const int j0 = (blockIdx.x & 7) * 256;
#pragma unroll 4
  for (int i = 0; i < 32; ++i) {
    const float w = Wc[(size_t)(k0 + i) * 2048 + j0 + tid];
    const u16 hi = f2b(w);
    th[tid * 40 + i] = hi;
    tl[tid * 40 + i] = f2b(w - b2f(hi));
  }
  __syncthreads();
  const int j = j0 + tid;
  const int blk = (j & 511) >> 4, g = j >> 9, jj = j & 15;
  u16* dh = w2hi + blk * 32768 + (g * 16 + jj) * 512 + k0;
  u16* dl = w2lo + blk * 32768 + (g * 16 + jj) * 512 + k0;
#pragma unroll
  for (int q = 0; q < 4; ++q) {
    *(uint4*)(dh + q * 8) = *(const uint4*)&th[tid * 40 + q * 8];
    *(uint4*)(dl + q * 8) = *(const uint4*)&tl[tid * 40 + q * 8];
  }
}

__global__ void __launch_bounds__(NT) slicelstm_kernel(
    const float* __restrict__ x, const float* __restrict__ biases,
    const float* __restrict__ bcg, float* __restrict__ out,
    const u16* __restrict__ w1hi, const u16* __restrict__ w1lo,
    const u16* __restrict__ w2hi, const u16* __restrict__ w2lo,
    u16* __restrict__ act_hi, u16* __restrict__ act_lo,
    u16* __restrict__ h_hi, u16* __restrict__ h_lo,
    float* __restrict__ cbuf, unsigned* __restrict__ cnt) {
  __shared__ __align__(16) u16 W1H[64 * 200];  // [row=g*16+jj][k 0..191] (+8 pad)
  __shared__ __align__(16) u16 W1L[64 * 200];
  __shared__ __align__(16) u16 W2H[64 * 520];  // [row=g*16+jj][k 0..511] (+8 pad)

  const int tid = threadIdx.x;
  const int blk = blockIdx.x;
  const int j0 = blk * 16;
  const int s = j0 >> 7;
  const int jbase = j0 & 127;

  // ---- one-time: stage prepped weights into LDS ----
  {
    const u16* s1h = w1hi + blk * 12288;
    const u16* s1l = w1lo + blk * 12288;
    for (int i = tid; i < 64 * 24; i += NT) {
      const int r = i / 24, ck = i % 24;
      *(uint4*)&W1H[r * 200 + ck * 8] = *(const uint4*)&s1h[r * 192 + ck * 8];
      *(uint4*)&W1L[r * 200 + ck * 8] = *(const uint4*)&s1l[r * 192 + ck * 8];
    }
    const u16* s2h = w2hi + blk * 32768;
    for (int i = tid; i < 64 * 64; i += NT) {
      const int r = i >> 6, ck = i & 63;
      *(uint4*)&W2H[r * 520 + ck * 8] = *(const uint4*)&s2h[r * 512 + ck * 8];
    }
  }
  __syncthreads();

  const int lane = tid & 63;
  const int mt = tid >> 6;        // wave id = M-tile (16 batch rows)
  const int lm = lane & 15;
  const int lq = lane >> 4;
  const int ko = lq * 8;          // fragment k offset: k = quad*8 + j
  const int arow = mt * 16 + lm;  // A-operand row (batch)

  float biasv[4], bcv[4];
#pragma unroll
  for (int g = 0; g < 4; ++g) {
    biasv[g] = biases[s * 512 + g * 128 + jbase + lm];
    bcv[g] = bcg[g * 512 + j0 + lm];
  }

  const u16 *p1h[4], *p1l[4], *p2h[4], *p2l[4], *ahr[4], *alr[4];
#pragma unroll
  for (int g = 0; g < 4; ++g) {
    p1h[g] = &W1H[(g * 16 + lm) * 200];
    p1l[g] = &W1L[(g * 16 + lm) * 200];
    p2h[g] = &W2H[(g * 16 + lm) * 520];
    p2l[g] = w2lo + blk * 32768 + (g * 16 + lm) * 512;
    ahr[g] = act_hi + (g * 64 + arow) * 512;
    alr[g] = act_lo + (g * 64 + arow) * 512;
  }
  const float* xrow = x + (size_t)arow * 512 * 256 + s * 64;
  const int hbase = arow * 512 + s * 128;

  unsigned epoch = 0;

  for (int t = 0; t < TSTEPS; ++t) {
    // ---- A-fragments for phase 1 (gate-independent) ----
    short8 xh[2], xl[2], hh[4], hl[4];
    {
      const float* xp = xrow + t * 256;
#pragma unroll
      for (int kt = 0; kt < 2; ++kt) split8(xp + kt * 32 + ko, xh[kt], xl[kt]);
#pragma unroll
      for (int kt = 0; kt < 4; ++kt) {
        hh[kt] = ld8(&h_hi[hbase + kt * 32 + ko]);
        hl[kt] = ld8(&h_lo[hbase + kt * 32 + ko]);
      }
    }

    // ---- phase 1: block-diag gates + activations -> act bufs ----
#pragma unroll
    for (int g = 0; g < 4; ++g) {
      floatx4 acc = {0.f, 0.f, 0.f, 0.f};
#pragma unroll
      for (int kt = 0; kt < 2; ++kt) {
        const short8 bh = ld8(p1h[g] + kt * 32 + ko);
        const short8 bl = ld8(p1l[g] + kt * 32 + ko);
        acc = __builtin_amdgcn_mfma_f32_16x16x32_bf16(xh[kt], bh, acc, 0, 0, 0);
        acc = __builtin_amdgcn_mfma_f32_16x16x32_bf16(xl[kt], bh, acc, 0, 0, 0);
        acc = __builtin_amdgcn_mfma_f32_16x16x32_bf16(xh[kt], bl, acc, 0, 0, 0);
      }
#pragma unroll
      for (int kt = 0; kt < 4; ++kt) {
        const short8 bh = ld8(p1h[g] + 64 + kt * 32 + ko);
        const short8 bl = ld8(p1l[g] + 64 + kt * 32 + ko);
        acc = __builtin_amdgcn_mfma_f32_16x16x32_bf16(hh[kt], bh, acc, 0, 0, 0);
        acc = __builtin_amdgcn_mfma_f32_16x16x32_bf16(hl[kt], bh, acc, 0, 0, 0);
        acc = __builtin_amdgcn_mfma_f32_16x16x32_bf16(hh[kt], bl, acc, 0, 0, 0);
      }
#pragma unroll
      for (int r = 0; r < 4; ++r) {  // C/D: col = lane&15, row = (lane>>4)*4 + r
        const int brow = mt * 16 + lq * 4 + r;
        const float pre = acc[r] + biasv[g];
        const float a = (g == 2) ? tanhf_fast(pre) : sigf(pre);
        const u16 ah = f2b(a);
        const u16 al = f2b(a - b2f(ah));
        const int o = (g * 64 + brow) * 512 + j0 + lm;
        act_hi[o] = ah;
        act_lo[o] = al;
      }
    }
    epoch++;
    grid_barrier(cnt, epoch * NB);

    // ---- phase 2: connector GEMM ----
    floatx4 acc2[4];
#pragma unroll
    for (int g = 0; g < 4; ++g) acc2[g] = (floatx4){0.f, 0.f, 0.f, 0.f};
#pragma unroll 4
    for (int kt = 0; kt < 16; ++kt) {
      const int kb = kt * 32 + ko;
#pragma unroll
      for (int g = 0; g < 4; ++g) {
        const short8 Ah = ld8(ahr[g] + kb);
        const short8 Al = ld8(alr[g] + kb);
        const short8 Bh = ld8(p2h[g] + kb);  // LDS
        const short8 Bl = ld8(p2l[g] + kb);  // global (L2-resident)
        acc2[g] = __builtin_amdgcn_mfma_f32_16x16x32_bf16(Ah, Bh, acc2[g], 0, 0, 0);
        acc2[g] = __builtin_amdgcn_mfma_f32_16x16x32_bf16(Al, Bh, acc2[g], 0, 0, 0);
        acc2[g] = __builtin_amdgcn_mfma_f32_16x16x32_bf16(Ah, Bl, acc2[g], 0, 0, 0);
      }
    }

    // ---- phase 3: elementwise LSTM update for own 16 columns ----
    {
      const int j = j0 + lm;
#pragma unroll
      for (int r = 0; r < 4; ++r) {
        const int brow = mt * 16 + lq * 4 + r;
        const float it = sigf(acc2[0][r] + bcv[0]);
        const float ft = sigf(acc2[1][r] + bcv[1]);
        const float gt = tanhf_fast(acc2[2][r] + bcv[2]);
        const float ot = sigf(acc2[3][r] + bcv[3]);
        const int ci = brow * 512 + j;
        const float cn = ft * cbuf[ci] + it * gt;
        cbuf[ci] = cn;
        const float h = ot * tanhf_fast(cn);
        const u16 hh2 = f2b(h);
        h_hi[ci] = hh2;
        h_lo[ci] = f2b(h - b2f(hh2));
        out[((size_t)(brow * TSTEPS + t)) * 512 + j] = h;  // hidden_seq f32
      }
    }
    epoch++;
    grid_barrier(cnt, epoch * NB);
  }

  // ---- final h_t, c_t ----
  for (int i2 = tid; i2 < 1024; i2 += NT) {
    const int b = i2 >> 4, jj = i2 & 15;
    const int idx = b * 512 + j0 + jj;
    out[16777216 + idx] = b2f(h_hi[idx]) + b2f(h_lo[idx]);
    out[16777216 + 32768 + idx] = cbuf[idx];
  }
}

extern "C" void kernel_launch(void* const* d_in, const int* in_sizes, int n_in,
                              void* d_out, int out_size, void* d_ws, size_t ws_size,
                              hipStream_t stream) {
  const float* x = (const float*)d_in[0];
  const float* Ws = (const float*)d_in[1];
  const float* Us = (const float*)d_in[2];
  const float* biases = (const float*)d_in[3];
  const float* Wc = (const float*)d_in[4];
  const float* bc = (const float*)d_in[5];

  char* ws = (char*)d_ws;
  unsigned* cnt = (unsigned*)(ws + WS_CNT);
  u16* act_hi = (u16*)(ws + WS_ACT_HI);
  u16* act_lo = (u16*)(ws + WS_ACT_LO);
  u16* h_hi = (u16*)(ws + WS_H_HI);
  u16* h_lo = (u16*)(ws + WS_H_LO);
  float* cbuf = (float*)(ws + WS_CBUF);
  u16* w1hi = (u16*)(ws + WS_W1HI);
  u16* w1lo = (u16*)(ws + WS_W1LO);
  u16* w2hi = (u16*)(ws + WS_W2HI);
  u16* w2lo = (u16*)(ws + WS_W2LO);

  hipLaunchKernelGGL(init_ws_kernel, dim3(256), dim3(NT), 0, stream, (unsigned*)ws,
                     WS_ZERO_BYTES / 4);
  hipLaunchKernelGGL(prep_w1_kernel, dim3(1536), dim3(NT), 0, stream, Ws, Us, w1hi, w1lo);
  hipLaunchKernelGGL(prep_w2_kernel, dim3(128), dim3(NT), 0, stream, Wc, w2hi, w2lo);
  hipLaunchKernelGGL(slicelstm_kernel, dim3(NB), dim3(NT), 0, stream, x, biases, bc,
                     (float*)d_out, w1hi, w1lo, w2hi, w2lo, act_hi, act_lo, h_hi, h_lo,
                     cbuf, cnt);
}